// Round 2
// baseline (446.885 us; speedup 1.0000x reference)
//
#include <hip/hip_runtime.h>
#include <hip/hip_bf16.h>

// Problem constants (fixed by setup_inputs)
#define E_    8
#define DIN   2048
#define DOUT  2048
#define N_TOK 4096
#define NK    8192
#define R_    16
#define KEXT  2112            // 2048 + 16 (LoRA rank tail) + 48 zero pad, %64==0
#define KT_N  (KEXT / 64)     // 33 K-tiles
#define BM    256
#define BN    256
#define MT_MAX 40             // worst-case sum_e ceil(Me/256) = 32 + 7 (+1 slack)

typedef __bf16 bf16x8 __attribute__((ext_vector_type(8)));
typedef float  f32x4  __attribute__((ext_vector_type(4)));

static __device__ __forceinline__ void gld16(const void* g, void* l) {
  __builtin_amdgcn_global_load_lds(
      (const __attribute__((address_space(1))) unsigned int*)g,
      (__attribute__((address_space(3))) unsigned int*)l, 16, 0, 0);
}

static __device__ __forceinline__ unsigned short f2bfu(float f) {
  union { float f; unsigned int u; } v; v.f = f;
  unsigned int r = v.u + 0x7fffu + ((v.u >> 16) & 1u);  // round-to-nearest-even
  return (unsigned short)(r >> 16);
}

// ---- fused prep: Wbe build | token gather | lora_A convert (independent, one launch) ----
// blocks [0,4096): Wbe rows (4 rows/block, 1 wave each): bf16(W) | bf16(loraB) | zeros
// blocks [4096,12288): gather slot s -> Xe row (bf16, stride KEXT) + gate/tok
// blocks [12288,12544): lora_A fp32 -> bf16 (1 float4/thread)
__global__ void __launch_bounds__(256)
k_prep(const float* __restrict__ w, const float* __restrict__ lb,
       unsigned short* __restrict__ wbe,
       const float* __restrict__ la, unsigned short* __restrict__ Ab,
       const float* __restrict__ x, const int* __restrict__ ssi,
       const float* __restrict__ gates, const int* __restrict__ kptr,
       unsigned short* __restrict__ Xe, float* __restrict__ gate,
       int* __restrict__ tok) {
  const int b = blockIdx.x, tid = threadIdx.x;
  if (b < 4096) {                                   // ---- wconv ----
    const int wv = tid >> 6, ln = tid & 63;
    const long long row = ((long long)b << 2) | wv; // e*DOUT + n
    const float4* src  = (const float4*)(w + row * DIN);
    const float4* lsrc = (const float4*)(lb + row * R_);
    ushort4* dst = (ushort4*)(wbe + row * KEXT);
    for (int u = ln; u < KEXT / 4; u += 64) {
      float4 v;
      if (u < 512)       v = src[u];
      else if (u < 516)  v = lsrc[u - 512];
      else               v = make_float4(0.f, 0.f, 0.f, 0.f);
      ushort4 o;
      o.x = f2bfu(v.x); o.y = f2bfu(v.y); o.z = f2bfu(v.z); o.w = f2bfu(v.w);
      dst[u] = o;
    }
  } else if (b < 12288) {                           // ---- gather ----
    const int s = b - 4096;
    int ssv = ssi[s];
    int kk = kptr[0];
    int t = ssv / kk, sl = ssv - t * kk;
    if (tid == 0) { gate[s] = gates[t * kk + sl]; tok[s] = t; }
    const float4* src = (const float4*)(x + (long long)t * DIN);
    ushort4* dst = (ushort4*)(Xe + (long long)s * KEXT);
    for (int i = tid; i < 512; i += 256) {
      float4 v = src[i];
      ushort4 o;
      o.x = f2bfu(v.x); o.y = f2bfu(v.y); o.z = f2bfu(v.z); o.w = f2bfu(v.w);
      dst[i] = o;
    }
    if (tid < 12) {   // zero cols 2064..2111 (XA slot 2048..2063 filled by k_xa)
      ushort4 z; z.x = z.y = z.z = z.w = 0;
      dst[516 + tid] = z;
    }
  } else {                                          // ---- aconv ----
    const int i = ((b - 12288) << 8) + tid;         // 65536 float4 total
    float4 v = ((const float4*)la)[i];
    ushort4 o;
    o.x = f2bfu(v.x); o.y = f2bfu(v.y); o.z = f2bfu(v.z); o.w = f2bfu(v.w);
    ((ushort4*)Ab)[i] = o;
  }
}

// ---- XA tail via MFMA: Xe[s][2048+r] = bf16( 2 * dot(x_s, lora_A[e][r]) ) ----
// Widened: 4 waves/block, each wave one K=512 slice of the same 16-slot tile;
// partial f32x4 accumulators reduced through LDS (4x the wave-parallelism of the
// old 1-wave version, which was 519 waves total = pure latency exposure).
__global__ void __launch_bounds__(256)
k_xa(unsigned short* __restrict__ Xe, const unsigned short* __restrict__ Ab,
     const int* __restrict__ eoff) {
  __shared__ f32x4 red[4][64];
  int tile = blockIdx.x;
  int off_prev = 0, e = -1, m_start = 0, m_end = 0, acc_t = 0;
#pragma unroll
  for (int i = 0; i < E_; i++) {
    int oe = eoff[i];
    int te = (oe - off_prev + 15) >> 4;
    if (e < 0 && tile < acc_t + te) {
      e = i; m_start = off_prev + (tile - acc_t) * 16; m_end = oe;
    }
    acc_t += te; off_prev = oe;
  }
  if (e < 0) return;
  const int tid = threadIdx.x;
  const int wv = tid >> 6, lane = tid & 63;
  const int l15 = lane & 15, quad = lane >> 4;
  int arow = m_start + l15; if (arow >= m_end) arow = m_end - 1;  // clamp partial tile
  const unsigned short* xp = Xe + (long long)arow * KEXT + wv * 512 + quad * 8;
  const unsigned short* bp = Ab + ((long long)e * R_ + l15) * DIN + wv * 512 + quad * 8;
  f32x4 acc = (f32x4){0.f, 0.f, 0.f, 0.f};
#pragma unroll 8
  for (int k0 = 0; k0 < 512; k0 += 32) {
    bf16x8 a = *(const bf16x8*)(xp + k0);
    bf16x8 b = *(const bf16x8*)(bp + k0);
    acc = __builtin_amdgcn_mfma_f32_16x16x32_bf16(a, b, acc, 0, 0, 0);
  }
  red[wv][lane] = acc;
  __syncthreads();
  if (wv == 0) {
    f32x4 s = red[0][lane] + red[1][lane] + red[2][lane] + red[3][lane];
#pragma unroll
    for (int t = 0; t < 4; t++) {
      int slot = m_start + quad * 4 + t;
      if (slot < m_end)
        Xe[(long long)slot * KEXT + 2048 + l15] = f2bfu(2.0f * s[t]);
    }
  }
}

// ---- grouped GEMM, 256x256 tile, 8 waves, dbuf BK=64, counted-vmcnt 2-phase + K-split ----
// T4: raw s_barrier + s_waitcnt vmcnt(8): next tile's 8 gld16/thread stay IN FLIGHT
// across the barrier while the current tile computes (no vmcnt(0) drain per K-tile).
// K-split 2 (kh): grid 640 half-jobs on 256 CUs @1 blk/CU -> 2.5 half-rounds = 1.25
// job-units vs 2.0 for the 320-job grid (tail quantization was the round-1 killer).
// Staged bytes unchanged; only the atomic epilogue doubles (L2-resident).
// XCD map: nt = id&7 fixed per XCD (dispatch round-robin), {mt,kh} within.
__global__ void __launch_bounds__(512, 2)
k_gemm(const unsigned short* __restrict__ Xe, const unsigned short* __restrict__ Wbe,
       const float* __restrict__ gate, const int* __restrict__ tok,
       const int* __restrict__ eoff, float* __restrict__ out) {
  __shared__ alignas(16) unsigned short sA[2][BM * 64];   // 64 KB
  __shared__ alignas(16) unsigned short sB[2][BN * 64];   // 64 KB
  __shared__ float gs[BM];
  __shared__ int   ts[BM];

  const int id  = blockIdx.x;          // 640 blocks
  const int nt  = id & 7;              // one n-tile per XCD slot
  const int jb  = id >> 3;             // 0..79
  const int kh  = jb & 1;              // K half
  const int mt  = jb >> 1;             // 0..39
  const int n_start = nt << 8;

  // m-tile scan, BM=256
  int off_prev = 0, e = -1, m_start = 0, m_end = 0, acc_t = 0;
#pragma unroll
  for (int i = 0; i < E_; i++) {
    int oe = eoff[i];
    int te = (oe - off_prev + 255) >> 8;
    if (e < 0 && mt < acc_t + te) {
      e = i; m_start = off_prev + (mt - acc_t) * 256; m_end = oe;
    }
    acc_t += te;
    off_prev = oe;
  }
  if (e < 0) return;

  const int tid = threadIdx.x;
  const int w = tid >> 6, lane = tid & 63;
  const int wm = w >> 2, wn = w & 3;              // 2M x 4N waves, 128x64 out each
  const int quad = lane >> 4, l15 = lane & 15;
  const int srow = lane >> 3;                     // row within 8-row staging chunk
  const int scol = ((lane & 7) ^ srow) * 8;       // SWIZZLED source bf16 col (BK=64)

  if (tid < 256) {   // stage gates/tokens; drained below, visible after 1st barrier
    int gm = m_start + tid; if (gm >= m_end) gm = m_end - 1;
    gs[tid] = gate[gm];
    ts[tid] = tok[gm];
  }

  f32x4 acc[8][4];
#pragma unroll
  for (int mi = 0; mi < 8; mi++)
#pragma unroll
    for (int ni = 0; ni < 4; ni++)
      acc[mi][ni] = (f32x4){0.f, 0.f, 0.f, 0.f};

  const unsigned short* Wb = Wbe + (long long)e * DOUT * KEXT;

  // stage one BK=64 K-tile into buffer `buf`: 8 gld16 per thread (4 jj x A,B)
#define STAGE(buf, kt_)                                                              \
  {                                                                                  \
    const int k0s = (kt_) * 64;                                                      \
    _Pragma("unroll")                                                                \
    for (int jj = 0; jj < 4; jj++) {                                                 \
      const int c = (w << 2) + jj;                                                   \
      const int rt = (c << 3) + srow;                                                \
      int ga = m_start + rt; if (ga >= m_end) ga = m_end - 1; /* clamp partial */    \
      gld16(Xe + (long long)ga * KEXT + k0s + scol, &sA[buf][(c << 9) + (lane << 3)]); \
      gld16(Wb + (long long)(n_start + rt) * KEXT + k0s + scol,                      \
            &sB[buf][(c << 9) + (lane << 3)]);                                       \
    }                                                                                \
  }

  const int kt_beg = kh * 17;          // kh0: tiles 0..16 (17), kh1: 17..32 (16)
  const int kt_end = kh ? KT_N : 17;

  // clean vm/lgkm slate so in-loop vmcnt(8) counts ONLY STAGE loads (gate/tok
  // vector loads + gs/ts ds_writes retired here; also makes gs/ts visible after
  // the first barrier)
  asm volatile("s_waitcnt vmcnt(0) lgkmcnt(0)" ::: "memory");
  STAGE(0, kt_beg);                    // 8 outstanding

  for (int kt = kt_beg; kt < kt_end; ++kt) {
    const int b = (kt - kt_beg) & 1;
    if (kt + 1 < kt_end) {
      STAGE(b ^ 1, kt + 1);            // 16 outstanding
      asm volatile("s_waitcnt vmcnt(8)" ::: "memory");   // my buf-b 8 landed
    } else {
      asm volatile("s_waitcnt vmcnt(0)" ::: "memory");   // final tile: full drain
    }
    __builtin_amdgcn_s_barrier();      // everyone's buf-b loads landed
    __builtin_amdgcn_sched_barrier(0); // pin ds_reads below the barrier (rule 18)
#pragma unroll
    for (int ks = 0; ks < 2; ks++) {
      // swizzled read: colchunk kc lives at slot kc^(row&7); row&7 == l15&7
      const int kx = (((ks << 2) | quad) ^ (l15 & 7)) << 3;
      bf16x8 af[8], bfr[4];
#pragma unroll
      for (int mi = 0; mi < 8; mi++)
        af[mi] = *(const bf16x8*)&sA[b][(wm * 128 + mi * 16 + l15) * 64 + kx];
#pragma unroll
      for (int ni = 0; ni < 4; ni++)
        bfr[ni] = *(const bf16x8*)&sB[b][(wn * 64 + ni * 16 + l15) * 64 + kx];
#pragma unroll
      for (int mi = 0; mi < 8; mi++)
#pragma unroll
        for (int ni = 0; ni < 4; ni++)
          acc[mi][ni] = __builtin_amdgcn_mfma_f32_16x16x32_bf16(
              af[mi], bfr[ni], acc[mi][ni], 0, 0, 0);
    }
    asm volatile("" ::: "memory");     // pin ds_reads above barrier #2
    __builtin_amdgcn_s_barrier();      // all waves done reading buf b
    __builtin_amdgcn_sched_barrier(0); // next STAGE may now overwrite it
  }
#undef STAGE

  // ---- epilogue: gate + atomic scatter (LoRA already in acc via K-tail) ----
#pragma unroll
  for (int mi = 0; mi < 8; mi++) {
    const int rbase = wm * 128 + mi * 16 + quad * 4;
#pragma unroll
    for (int t4 = 0; t4 < 4; t4++) {
      const int row = rbase + t4;
      if (m_start + row >= m_end) continue;    // partial tile guard
      const float g = gs[row];
      float* orow = out + (long long)ts[row] * DOUT + n_start + wn * 64 + l15;
#pragma unroll
      for (int ni = 0; ni < 4; ni++)
        atomicAdd(orow + ni * 16, acc[mi][ni][t4] * g);  // k=2 routes x 2 kh adds
    }
  }
}

extern "C" void kernel_launch(void* const* d_in, const int* in_sizes, int n_in,
                              void* d_out, int out_size, void* d_ws, size_t ws_size,
                              hipStream_t stream) {
  (void)in_sizes; (void)n_in; (void)out_size; (void)ws_size;
  const float* inputs = (const float*)d_in[0];
  const float* weight = (const float*)d_in[1];
  const float* lora_A = (const float*)d_in[2];
  const float* lora_B = (const float*)d_in[3];
  const float* gates  = (const float*)d_in[4];
  const int* sei  = (const int*)d_in[5];
  const int* ssi  = (const int*)d_in[6];
  const int* eoff = (const int*)d_in[7];
  const int* kptr = (const int*)d_in[8];
  (void)sei;
  float* out = (float*)d_out;

  // workspace layout (~104.4 MB)
  unsigned char* ws = (unsigned char*)d_ws;
  unsigned short* Wbe = (unsigned short*)ws;                 // 8*2048*2112*2 = 69,206,016 B
  unsigned short* Xe  = (unsigned short*)(ws + 69206016);    // 8192*2112*2   = 34,603,008 B
  unsigned short* Ab  = (unsigned short*)(ws + 103809024);   // 8*16*2048*2   =    524,288 B
  float* gate = (float*)(ws + 104333312);                    // 8192*4
  int*   tok  = (int*)(ws + 104366080);                      // 8192*4

  hipMemsetAsync(d_out, 0, (size_t)N_TOK * DOUT * sizeof(float), stream);
  k_prep<<<4096 + 8192 + 256, 256, 0, stream>>>(weight, lora_B, Wbe, lora_A, Ab,
                                                inputs, ssi, gates, kptr, Xe, gate, tok);
  k_xa<<<519, 256, 0, stream>>>(Xe, Ab, eoff);
  k_gemm<<<MT_MAX * 8 * 2, 512, 0, stream>>>(Xe, Wbe, gate, tok, eoff, out);
}